// Round 1
// baseline (2248.732 us; speedup 1.0000x reference)
//
#include <hip/hip_runtime.h>
#include <math.h>

#define NN 50000
#define NE 600000
#define NG 1000
#define HC 32

// ---------------- setup kernels ----------------

__global__ __launch_bounds__(256) void k_deg(const int* __restrict__ dst, int* __restrict__ deg) {
    int e = blockIdx.x * 256 + threadIdx.x;
    if (e < NE) atomicAdd(&deg[dst[e]], 1);
}

__global__ __launch_bounds__(1024) void k_scan(const int* __restrict__ deg, int* __restrict__ rowstart,
                                               float* __restrict__ dinv) {
    __shared__ int sums[1024];
    int t = threadIdx.x;
    const int chunk = (NN + 1023) / 1024;
    int b0 = t * chunk;
    int e0 = min(b0 + chunk, NN);
    int s = 0;
    for (int i = b0; i < e0; i++) s += deg[i];
    sums[t] = s;
    __syncthreads();
    for (int o = 1; o < 1024; o <<= 1) {
        int v = (t >= o) ? sums[t - o] : 0;
        __syncthreads();
        sums[t] += v;
        __syncthreads();
    }
    int run = (t > 0) ? sums[t - 1] : 0;
    for (int i = b0; i < e0; i++) {
        rowstart[i] = run;
        int d = deg[i];
        run += d;
        dinv[i] = d > 0 ? rsqrtf((float)d) : 0.f;
    }
    if (t == 1023) rowstart[NN] = sums[1023];
}

__global__ __launch_bounds__(256) void k_csr(const int* __restrict__ src, const int* __restrict__ dst,
                                             const int* __restrict__ rowstart, int* __restrict__ cursor,
                                             int* __restrict__ csr_src) {
    int e = blockIdx.x * 256 + threadIdx.x;
    if (e < NE) {
        int d = dst[e];
        int p = atomicAdd(&cursor[d], 1);
        csr_src[rowstart[d] + p] = src[e];
    }
}

__global__ __launch_bounds__(256) void k_atom(const int* __restrict__ x, const float* __restrict__ emb,
                                              float* __restrict__ h) {
    int idx = blockIdx.x * 256 + threadIdx.x;
    if (idx >= NN * HC) return;
    int n = idx >> 5, c = idx & 31;
    float s = 0.f;
#pragma unroll
    for (int j = 0; j < 9; j++) {
        int v = x[n * 9 + j];
        s += emb[(j * 100 + v) * HC + c];
    }
    h[idx] = s;
}

// ---------------- generic [N,32]@[32,32] matmul ----------------
// out = ACT( (in (+preb)) @ W + bias )
// ACT: 0=none 1=relu 2=softplus
template <int ACT, bool PREB, bool BIAS>
__global__ __launch_bounds__(256) void k_mm(const float* __restrict__ in, const float* __restrict__ W,
                                            const float* __restrict__ bias, const float* __restrict__ preb,
                                            float* __restrict__ out) {
    __shared__ float wl[HC * HC];
    __shared__ float il[8][HC];
    int t = threadIdx.x;
    for (int i = t; i < HC * HC; i += 256) wl[i] = W[i];
    int slot = t >> 5, c = t & 31;
    int n = blockIdx.x * 8 + slot;
    float v = 0.f;
    if (n < NN) {
        v = in[n * HC + c];
        if (PREB) v += preb[c];
    }
    il[slot][c] = v;
    __syncthreads();
    if (n >= NN) return;
    float s = BIAS ? bias[c] : 0.f;
#pragma unroll
    for (int k = 0; k < HC; k++) s += il[slot][k] * wl[k * HC + c];
    if (ACT == 1) s = fmaxf(s, 0.f);
    else if (ACT == 2) s = (s > 20.f) ? s : log1pf(expf(s));
    out[n * HC + c] = s;
}

// ---------------- fused aggregation + GRU ----------------
// AGGR: 0 = min, 1 = product (sign-parity * exp(sum log|m|))
template <int AGGR, bool POSTRELU>
__global__ __launch_bounds__(256) void k_agg_gru(const float* __restrict__ hw, float* __restrict__ h,
                                                 const int* __restrict__ rowstart, const int* __restrict__ csr_src,
                                                 const float* __restrict__ wih, const float* __restrict__ whh,
                                                 const float* __restrict__ bih, const float* __restrict__ bhh) {
    __shared__ float wi[HC][3 * HC];  // wi[k][row] = wih[row*HC + k]
    __shared__ float wh[HC][3 * HC];
    __shared__ float al[8][HC];
    __shared__ float hl[8][HC];
    int t = threadIdx.x;
    for (int i = t; i < 3 * HC * HC; i += 256) {
        int row = i >> 5, k = i & 31;
        wi[k][row] = wih[i];
        wh[k][row] = whh[i];
    }
    int slot = t >> 5, c = t & 31;
    int n = blockIdx.x * 8 + slot;
    float a = 0.f, hv = 0.f;
    if (n < NN) {
        int rs = rowstart[n], re = rowstart[n + 1];
        if (AGGR == 0) {
            float m = 3.0e38f;
            for (int e = rs; e < re; e++) {
                int s = csr_src[e];
                m = fminf(m, hw[s * HC + c]);
            }
            a = (re > rs) ? m : 0.f;
        } else {
            float logs = 0.f;
            int neg = 0;
            for (int e = rs; e < re; e++) {
                int s = csr_src[e];
                float v = hw[s * HC + c];
                neg += (v < 0.f) ? 1 : 0;
                logs += logf(fabsf(v));
            }
            float ex = expf(logs);
            a = (re > rs) ? ((neg & 1) ? -ex : ex) : 0.f;
        }
        hv = h[n * HC + c];
    }
    al[slot][c] = a;
    hl[slot][c] = hv;
    __syncthreads();
    if (n >= NN) return;
    float gir = bih[c], giz = bih[HC + c], gin = bih[2 * HC + c];
    float ghr = bhh[c], ghz = bhh[HC + c], ghn = bhh[2 * HC + c];
#pragma unroll
    for (int k = 0; k < HC; k++) {
        float ak = al[slot][k], hk = hl[slot][k];
        gir += ak * wi[k][c];
        ghr += hk * wh[k][c];
        giz += ak * wi[k][HC + c];
        ghz += hk * wh[k][HC + c];
        gin += ak * wi[k][2 * HC + c];
        ghn += hk * wh[k][2 * HC + c];
    }
    float r = 1.f / (1.f + expf(-(gir + ghr)));
    float z = 1.f / (1.f + expf(-(giz + ghz)));
    float nn = tanhf(gin + r * ghn);
    float hn = (1.f - z) * nn + z * hv;
    if (POSTRELU) hn = fmaxf(hn, 0.f);
    h[n * HC + c] = hn;
}

// ---------------- conv2: GraphConv sum + two matmuls + ELU ----------------
__global__ __launch_bounds__(256) void k_conv2(const float* __restrict__ h, float* __restrict__ out,
                                               const int* __restrict__ rowstart, const int* __restrict__ csr_src,
                                               const float* __restrict__ rel_w, const float* __restrict__ rel_b,
                                               const float* __restrict__ root_w) {
    __shared__ float rw[HC * HC], ow[HC * HC];
    __shared__ float sl[8][HC], hl[8][HC];
    int t = threadIdx.x;
    for (int i = t; i < HC * HC; i += 256) {
        rw[i] = rel_w[i];
        ow[i] = root_w[i];
    }
    int slot = t >> 5, c = t & 31;
    int n = blockIdx.x * 8 + slot;
    float s = 0.f, hv = 0.f;
    if (n < NN) {
        int rs = rowstart[n], re = rowstart[n + 1];
        for (int e = rs; e < re; e++) s += h[csr_src[e] * HC + c];
        hv = h[n * HC + c];
    }
    sl[slot][c] = s;
    hl[slot][c] = hv;
    __syncthreads();
    if (n >= NN) return;
    float o = rel_b[c];
#pragma unroll
    for (int k = 0; k < HC; k++) o += sl[slot][k] * rw[k * HC + c] + hl[slot][k] * ow[k * HC + c];
    o = (o > 0.f) ? o : expm1f(o);
    out[n * HC + c] = o;
}

// ---------------- bn2 (batch stats over all nodes) ----------------
__global__ __launch_bounds__(256) void k_bnred(const float* __restrict__ h, float* __restrict__ acc) {
    __shared__ float ls[8][HC], lq[8][HC];
    int t = threadIdx.x, slot = t >> 5, c = t & 31;
    float s = 0.f, q = 0.f;
    for (int n = blockIdx.x * 8 + slot; n < NN; n += gridDim.x * 8) {
        float v = h[n * HC + c];
        s += v;
        q += v * v;
    }
    ls[slot][c] = s;
    lq[slot][c] = q;
    __syncthreads();
    if (slot == 0) {
        for (int i = 1; i < 8; i++) {
            s += ls[i][c];
            q += lq[i][c];
        }
        atomicAdd(&acc[c], s);
        atomicAdd(&acc[HC + c], q);
    }
}

__global__ __launch_bounds__(256) void k_bnapply(float* __restrict__ h, const float* __restrict__ acc,
                                                 const float* __restrict__ g, const float* __restrict__ b) {
    int idx = blockIdx.x * 256 + threadIdx.x;
    if (idx >= NN * HC) return;
    int c = idx & 31;
    float mu = acc[c] * (1.f / NN);
    float var = acc[HC + c] * (1.f / NN) - mu * mu;
    h[idx] = (h[idx] - mu) * rsqrtf(var + 1e-5f) * g[c] + b[c];
}

// ---------------- TAGConv step: cur_new = D^-1/2 A D^-1/2 cur ; acc += cur_new @ Wk ----------------
__global__ __launch_bounds__(256) void k_tag(const float* __restrict__ cur, float* __restrict__ curnew,
                                             float* __restrict__ acc, const float* __restrict__ w4k,
                                             const int* __restrict__ rowstart, const int* __restrict__ csr_src,
                                             const float* __restrict__ dinv) {
    __shared__ float wl[HC * HC];
    __shared__ float cl[8][HC];
    int t = threadIdx.x;
    for (int i = t; i < HC * HC; i += 256) wl[i] = w4k[i];
    int slot = t >> 5, c = t & 31;
    int n = blockIdx.x * 8 + slot;
    float s = 0.f;
    if (n < NN) {
        int rs = rowstart[n], re = rowstart[n + 1];
        for (int e = rs; e < re; e++) {
            int sr = csr_src[e];
            s += dinv[sr] * cur[sr * HC + c];
        }
        s *= dinv[n];
        curnew[n * HC + c] = s;
    }
    cl[slot][c] = s;
    __syncthreads();
    if (n >= NN) return;
    float o = 0.f;
#pragma unroll
    for (int k = 0; k < HC; k++) o += cl[slot][k] * wl[k * HC + c];
    acc[n * HC + c] += o;
}

// ---------------- conv5: SAGE with Var aggregation ----------------
__global__ __launch_bounds__(256) void k_sage(const float* __restrict__ h, float* __restrict__ out,
                                              const int* __restrict__ rowstart, const int* __restrict__ csr_src,
                                              const float* __restrict__ lw, const float* __restrict__ lb,
                                              const float* __restrict__ rw_) {
    __shared__ float wl[HC * HC], wr[HC * HC];
    __shared__ float vl[8][HC], hl[8][HC];
    int t = threadIdx.x;
    for (int i = t; i < HC * HC; i += 256) {
        wl[i] = lw[i];
        wr[i] = rw_[i];
    }
    int slot = t >> 5, c = t & 31;
    int n = blockIdx.x * 8 + slot;
    float var = 0.f, hv = 0.f;
    if (n < NN) {
        int rs = rowstart[n], re = rowstart[n + 1];
        float s = 0.f, q = 0.f;
        for (int e = rs; e < re; e++) {
            float v = h[csr_src[e] * HC + c];
            s += v;
            q += v * v;
        }
        float dc = fmaxf((float)(re - rs), 1.f);
        float mean = s / dc, mean2 = q / dc;
        var = mean2 - mean * mean;
        hv = h[n * HC + c];
    }
    vl[slot][c] = var;
    hl[slot][c] = hv;
    __syncthreads();
    if (n >= NN) return;
    float o = lb[c];
#pragma unroll
    for (int k = 0; k < HC; k++) o += vl[slot][k] * wl[k * HC + c] + hl[slot][k] * wr[k * HC + c];
    out[n * HC + c] = o;
}

// ---------------- per-graph InstanceNorm + global max pool + final linear ----------------
__global__ __launch_bounds__(256) void k_final(const float* __restrict__ h, const int* __restrict__ batch,
                                               const float* __restrict__ linw, const float* __restrict__ linb,
                                               float* __restrict__ out) {
    __shared__ float r1[8][HC];
    __shared__ float r2[8][HC];
    __shared__ float gmv[HC], grs[HC], pooled[HC];
    int g = blockIdx.x;
    int t = threadIdx.x, slot = t >> 5, c = t & 31;
    int lo = 0, hi = NN;
    while (lo < hi) {
        int mid = (lo + hi) >> 1;
        if (batch[mid] < g) lo = mid + 1;
        else hi = mid;
    }
    int start = lo;
    hi = NN;
    while (lo < hi) {
        int mid = (lo + hi) >> 1;
        if (batch[mid] <= g) lo = mid + 1;
        else hi = mid;
    }
    int end = lo;
    int cnt = end - start;
    float s = 0.f, q = 0.f;
    for (int n = start + slot; n < end; n += 8) {
        float v = h[n * HC + c];
        s += v;
        q += v * v;
    }
    r1[slot][c] = s;
    r2[slot][c] = q;
    __syncthreads();
    if (slot == 0) {
        for (int i = 1; i < 8; i++) {
            s += r1[i][c];
            q += r2[i][c];
        }
        float dc = (cnt > 0) ? (float)cnt : 1.f;
        float m = s / dc;
        float v = fmaxf(q / dc - m * m, 0.f);
        gmv[c] = m;
        grs[c] = rsqrtf(v + 1e-5f);
    }
    __syncthreads();
    float m_ = gmv[c], r_ = grs[c];
    float mx = -3.0e38f;
    for (int n = start + slot; n < end; n += 8) mx = fmaxf(mx, (h[n * HC + c] - m_) * r_);
    r1[slot][c] = mx;
    __syncthreads();
    if (slot == 0) {
        for (int i = 1; i < 8; i++) mx = fmaxf(mx, r1[i][c]);
        pooled[c] = (cnt > 0) ? mx : 0.f;
    }
    __syncthreads();
    if (t < 2) {
        float o = linb[t];
        for (int k = 0; k < HC; k++) o += pooled[k] * linw[k * 2 + t];
        out[g * 2 + t] = o;
    }
}

// ---------------- launch ----------------

extern "C" void kernel_launch(void* const* d_in, const int* in_sizes, int n_in,
                              void* d_out, int out_size, void* d_ws, size_t ws_size,
                              hipStream_t stream) {
    const int*   x      = (const int*)d_in[0];
    const int*   ei     = (const int*)d_in[1];
    const int*   batch  = (const int*)d_in[2];
    const float* emb    = (const float*)d_in[3];
    const float* w1     = (const float*)d_in[4];
    const float* g1wih  = (const float*)d_in[5];
    const float* g1whh  = (const float*)d_in[6];
    const float* g1bih  = (const float*)d_in[7];
    const float* g1bhh  = (const float*)d_in[8];
    const float* rel_w  = (const float*)d_in[9];
    const float* rel_b  = (const float*)d_in[10];
    const float* root_w = (const float*)d_in[11];
    const float* bn2g   = (const float*)d_in[12];
    const float* bn2b   = (const float*)d_in[13];
    const float* w3     = (const float*)d_in[14];
    const float* g3wih  = (const float*)d_in[15];
    const float* g3whh  = (const float*)d_in[16];
    const float* g3bih  = (const float*)d_in[17];
    const float* g3bhh  = (const float*)d_in[18];
    const float* lin3w  = (const float*)d_in[19];
    const float* lin3b  = (const float*)d_in[20];
    const float* w4     = (const float*)d_in[21];
    const float* b4     = (const float*)d_in[22];
    const float* lin4w  = (const float*)d_in[23];
    const float* lin4b  = (const float*)d_in[24];
    const float* sagelw = (const float*)d_in[25];
    const float* sagelb = (const float*)d_in[26];
    const float* sagerw = (const float*)d_in[27];
    const float* lin5w  = (const float*)d_in[28];
    const float* lin5b  = (const float*)d_in[29];
    const float* linw   = (const float*)d_in[30];
    const float* linb   = (const float*)d_in[31];

    const int* src = ei;
    const int* dst = ei + NE;

    char* ws = (char*)d_ws;
    size_t off = 0;
    int* deg = (int*)(ws + off); off += (size_t)NN * 4;
    int* cursor = (int*)(ws + off); off += (size_t)NN * 4;
    float* bnacc = (float*)(ws + off); off += 64 * 4;
    size_t zbytes = off;
    int* rowstart = (int*)(ws + off); off += (size_t)(NN + 1) * 4;
    float* dinv = (float*)(ws + off); off += (size_t)NN * 4;
    int* csr = (int*)(ws + off); off += (size_t)NE * 4;
    float* A = (float*)(ws + off); off += (size_t)NN * HC * 4;
    float* B = (float*)(ws + off); off += (size_t)NN * HC * 4;
    float* C = (float*)(ws + off); off += (size_t)NN * HC * 4;

    hipMemsetAsync(ws, 0, zbytes, stream);

    int ngE = (NE + 255) / 256;
    int ngN8 = (NN + 7) / 8;
    int ngNC = (NN * HC + 255) / 256;

    k_deg<<<ngE, 256, 0, stream>>>(dst, deg);
    k_scan<<<1, 1024, 0, stream>>>(deg, rowstart, dinv);
    k_csr<<<ngE, 256, 0, stream>>>(src, dst, rowstart, cursor, csr);
    k_atom<<<ngNC, 256, 0, stream>>>(x, emb, A);

    // conv1: GatedGraphConv(4 layers, min), then relu
    for (int i = 0; i < 4; i++) {
        k_mm<0, false, false><<<ngN8, 256, 0, stream>>>(A, w1 + (size_t)i * HC * HC, nullptr, nullptr, B);
        if (i < 3)
            k_agg_gru<0, false><<<ngN8, 256, 0, stream>>>(B, A, rowstart, csr, g1wih, g1whh, g1bih, g1bhh);
        else
            k_agg_gru<0, true><<<ngN8, 256, 0, stream>>>(B, A, rowstart, csr, g1wih, g1whh, g1bih, g1bhh);
    }

    // conv2 + elu -> B, then bn2 in-place
    k_conv2<<<ngN8, 256, 0, stream>>>(A, B, rowstart, csr, rel_w, rel_b, root_w);
    k_bnred<<<256, 256, 0, stream>>>(B, bnacc);
    k_bnapply<<<ngNC, 256, 0, stream>>>(B, bnacc, bn2g, bn2b);

    // conv3: GatedGraphConv(5 layers, mul), then relu(lin3)
    for (int i = 0; i < 5; i++) {
        k_mm<0, false, false><<<ngN8, 256, 0, stream>>>(B, w3 + (size_t)i * HC * HC, nullptr, nullptr, A);
        k_agg_gru<1, false><<<ngN8, 256, 0, stream>>>(A, B, rowstart, csr, g3wih, g3whh, g3bih, g3bhh);
    }
    k_mm<1, false, true><<<ngN8, 256, 0, stream>>>(B, lin3w, lin3b, nullptr, B);

    // conv4: TAGConv K=7 -> acc in C; then softplus(lin4(C + b4)) -> B
    k_mm<0, false, false><<<ngN8, 256, 0, stream>>>(B, w4, nullptr, nullptr, C);
    {
        float* cur = B;
        float* nxt = A;
        for (int k = 1; k < 8; k++) {
            k_tag<<<ngN8, 256, 0, stream>>>(cur, nxt, C, w4 + (size_t)k * HC * HC, rowstart, csr, dinv);
            float* tmp = cur; cur = nxt; nxt = tmp;
        }
    }
    k_mm<2, true, true><<<ngN8, 256, 0, stream>>>(C, lin4w, lin4b, b4, B);

    // conv5: SAGE var-aggr -> A; softplus(lin5) in-place
    k_sage<<<ngN8, 256, 0, stream>>>(B, A, rowstart, csr, sagelw, sagelb, sagerw);
    k_mm<2, false, true><<<ngN8, 256, 0, stream>>>(A, lin5w, lin5b, nullptr, A);

    // bn5 (per-graph InstanceNorm) + max pool + final linear
    k_final<<<NG, 256, 0, stream>>>(A, batch, linw, linb, (float*)d_out);
}

// Round 2
// 1529.419 us; speedup vs baseline: 1.4703x; 1.4703x over previous
//
#include <hip/hip_runtime.h>
#include <math.h>

#define NN 50000   // divisible by 8 -> every 8-node block is full
#define NE 600000
#define NG 1000
#define HC 32

__device__ __forceinline__ float softplusf(float s) {
    return fmaxf(s, 0.f) + log1pf(expf(-fabsf(s)));
}

// ---------------- setup kernels ----------------

__global__ __launch_bounds__(256) void k_deg(const int* __restrict__ dst, int* __restrict__ deg) {
    int e = blockIdx.x * 256 + threadIdx.x;
    if (e < NE) atomicAdd(&deg[dst[e]], 1);
}

__global__ __launch_bounds__(1024) void k_scan(const int* __restrict__ deg, int* __restrict__ rowstart,
                                               float* __restrict__ dinv) {
    __shared__ int sums[1024];
    int t = threadIdx.x;
    const int chunk = (NN + 1023) / 1024;
    int b0 = t * chunk;
    int e0 = min(b0 + chunk, NN);
    int s = 0;
    for (int i = b0; i < e0; i++) s += deg[i];
    sums[t] = s;
    __syncthreads();
    for (int o = 1; o < 1024; o <<= 1) {
        int v = (t >= o) ? sums[t - o] : 0;
        __syncthreads();
        sums[t] += v;
        __syncthreads();
    }
    int run = (t > 0) ? sums[t - 1] : 0;
    for (int i = b0; i < e0; i++) {
        rowstart[i] = run;
        int d = deg[i];
        run += d;
        dinv[i] = d > 0 ? rsqrtf((float)d) : 0.f;
    }
    if (t == 1023) rowstart[NN] = sums[1023];
}

__global__ __launch_bounds__(256) void k_csr(const int* __restrict__ src, const int* __restrict__ dst,
                                             const int* __restrict__ rowstart, int* __restrict__ cursor,
                                             int* __restrict__ csr_src) {
    int e = blockIdx.x * 256 + threadIdx.x;
    if (e < NE) {
        int d = dst[e];
        int p = atomicAdd(&cursor[d], 1);
        csr_src[rowstart[d] + p] = src[e];
    }
}

__global__ __launch_bounds__(256) void k_atom(const int* __restrict__ x, const float* __restrict__ emb,
                                              float* __restrict__ h) {
    int idx = blockIdx.x * 256 + threadIdx.x;
    int n = idx >> 5, c = idx & 31;
    float s = 0.f;
#pragma unroll
    for (int j = 0; j < 9; j++) {
        int v = x[n * 9 + j];
        s += emb[(j * 100 + v) * HC + c];
    }
    h[idx] = s;
}

// ---------------- generic [N,32]@[32,32] matmul (conv1 initial) ----------------
__global__ __launch_bounds__(256) void k_mm(const float* __restrict__ in, const float* __restrict__ W,
                                            float* __restrict__ out) {
    __shared__ float wl[HC * HC];
    __shared__ float il[8][HC];
    int t = threadIdx.x;
    for (int i = t; i < HC * HC; i += 256) wl[i] = W[i];
    int slot = t >> 5, c = t & 31;
    int n = blockIdx.x * 8 + slot;
    il[slot][c] = in[n * HC + c];
    __syncthreads();
    float s = 0.f;
#pragma unroll
    for (int k = 0; k < HC; k++) s += il[slot][k] * wl[k * HC + c];
    out[n * HC + c] = s;
}

// ---------------- fused aggregation + GRU (+ optional next-layer transform) ----------------
// AGGR: 0 = min, 1 = product. EPI: 0 none, 1 out_next = h_new @ Wn, 2 out_next = relu(h_new @ Wn + nb)
template <int AGGR, bool POSTRELU, int EPI>
__global__ __launch_bounds__(256) void k_agg_gru(const float* __restrict__ hw, float* __restrict__ h,
                                                 const int* __restrict__ rowstart, const int* __restrict__ csr_src,
                                                 const float* __restrict__ wih, const float* __restrict__ whh,
                                                 const float* __restrict__ bih, const float* __restrict__ bhh,
                                                 const float* __restrict__ Wn, const float* __restrict__ nb,
                                                 float* __restrict__ out_next) {
    __shared__ float wi[HC][3 * HC + 1];  // padded: stride 97 -> conflict-free transpose store
    __shared__ float wh[HC][3 * HC + 1];
    __shared__ float wn[EPI > 0 ? HC * HC : 1];
    __shared__ float al[8][HC];
    __shared__ float hl[8][HC];
    int t = threadIdx.x;
    for (int i = t; i < 3 * HC * HC; i += 256) {
        int row = i >> 5, k = i & 31;
        wi[k][row] = wih[i];
        wh[k][row] = whh[i];
    }
    if (EPI > 0) {
        for (int i = t; i < HC * HC; i += 256) wn[i] = Wn[i];
    }
    int slot = t >> 5, c = t & 31;
    int n = blockIdx.x * 8 + slot;
    int rs = rowstart[n], re = rowstart[n + 1];
    float a;
    if (AGGR == 0) {
        float m = 3.0e38f;
        int e = rs;
        for (; e + 3 < re; e += 4) {
            int s0 = csr_src[e], s1 = csr_src[e + 1], s2 = csr_src[e + 2], s3 = csr_src[e + 3];
            float v0 = hw[s0 * HC + c], v1 = hw[s1 * HC + c];
            float v2 = hw[s2 * HC + c], v3 = hw[s3 * HC + c];
            m = fminf(m, fminf(fminf(v0, v1), fminf(v2, v3)));
        }
        for (; e < re; e++) m = fminf(m, hw[csr_src[e] * HC + c]);
        a = (re > rs) ? m : 0.f;
    } else {
        float logs = 0.f;
        int neg = 0;
        int e = rs;
        for (; e + 3 < re; e += 4) {
            int s0 = csr_src[e], s1 = csr_src[e + 1], s2 = csr_src[e + 2], s3 = csr_src[e + 3];
            float v0 = hw[s0 * HC + c], v1 = hw[s1 * HC + c];
            float v2 = hw[s2 * HC + c], v3 = hw[s3 * HC + c];
            neg += ((v0 < 0.f) ? 1 : 0) + ((v1 < 0.f) ? 1 : 0) + ((v2 < 0.f) ? 1 : 0) + ((v3 < 0.f) ? 1 : 0);
            logs += logf(fabsf(v0)) + logf(fabsf(v1)) + logf(fabsf(v2)) + logf(fabsf(v3));
        }
        for (; e < re; e++) {
            float v = hw[csr_src[e] * HC + c];
            neg += (v < 0.f) ? 1 : 0;
            logs += logf(fabsf(v));
        }
        float ex = expf(logs);
        a = (re > rs) ? ((neg & 1) ? -ex : ex) : 0.f;
    }
    float hv = h[n * HC + c];
    al[slot][c] = a;
    hl[slot][c] = hv;
    __syncthreads();
    float gir = bih[c], giz = bih[HC + c], gin = bih[2 * HC + c];
    float ghr = bhh[c], ghz = bhh[HC + c], ghn = bhh[2 * HC + c];
#pragma unroll
    for (int k = 0; k < HC; k++) {
        float ak = al[slot][k], hk = hl[slot][k];
        gir += ak * wi[k][c];
        ghr += hk * wh[k][c];
        giz += ak * wi[k][HC + c];
        ghz += hk * wh[k][HC + c];
        gin += ak * wi[k][2 * HC + c];
        ghn += hk * wh[k][2 * HC + c];
    }
    float r = 1.f / (1.f + expf(-(gir + ghr)));
    float z = 1.f / (1.f + expf(-(giz + ghz)));
    float nnv = tanhf(gin + r * ghn);
    float hn = (1.f - z) * nnv + z * hv;
    if (POSTRELU) hn = fmaxf(hn, 0.f);
    h[n * HC + c] = hn;
    if (EPI > 0) {
        __syncthreads();
        hl[slot][c] = hn;
        __syncthreads();
        float o = (EPI == 2) ? nb[c] : 0.f;
#pragma unroll
        for (int k = 0; k < HC; k++) o += hl[slot][k] * wn[k * HC + c];
        if (EPI == 2) o = fmaxf(o, 0.f);
        out_next[n * HC + c] = o;
    }
}

// ---------------- conv2: GraphConv sum + two matmuls + ELU ----------------
__global__ __launch_bounds__(256) void k_conv2(const float* __restrict__ h, float* __restrict__ out,
                                               const int* __restrict__ rowstart, const int* __restrict__ csr_src,
                                               const float* __restrict__ rel_w, const float* __restrict__ rel_b,
                                               const float* __restrict__ root_w) {
    __shared__ float rw[HC * HC], ow[HC * HC];
    __shared__ float sl[8][HC], hl[8][HC];
    int t = threadIdx.x;
    for (int i = t; i < HC * HC; i += 256) {
        rw[i] = rel_w[i];
        ow[i] = root_w[i];
    }
    int slot = t >> 5, c = t & 31;
    int n = blockIdx.x * 8 + slot;
    int rs = rowstart[n], re = rowstart[n + 1];
    float s = 0.f;
    int e = rs;
    for (; e + 3 < re; e += 4) {
        int s0 = csr_src[e], s1 = csr_src[e + 1], s2 = csr_src[e + 2], s3 = csr_src[e + 3];
        s += h[s0 * HC + c] + h[s1 * HC + c] + h[s2 * HC + c] + h[s3 * HC + c];
    }
    for (; e < re; e++) s += h[csr_src[e] * HC + c];
    float hv = h[n * HC + c];
    sl[slot][c] = s;
    hl[slot][c] = hv;
    __syncthreads();
    float o = rel_b[c];
#pragma unroll
    for (int k = 0; k < HC; k++) o += sl[slot][k] * rw[k * HC + c] + hl[slot][k] * ow[k * HC + c];
    o = (o > 0.f) ? o : expm1f(o);
    out[n * HC + c] = o;
}

// ---------------- bn2 reduce ----------------
__global__ __launch_bounds__(256) void k_bnred(const float* __restrict__ h, float* __restrict__ acc) {
    __shared__ float ls[8][HC], lq[8][HC];
    int t = threadIdx.x, slot = t >> 5, c = t & 31;
    float s = 0.f, q = 0.f;
    for (int n = blockIdx.x * 8 + slot; n < NN; n += gridDim.x * 8) {
        float v = h[n * HC + c];
        s += v;
        q += v * v;
    }
    ls[slot][c] = s;
    lq[slot][c] = q;
    __syncthreads();
    if (slot == 0) {
        for (int i = 1; i < 8; i++) {
            s += ls[i][c];
            q += lq[i][c];
        }
        atomicAdd(&acc[c], s);
        atomicAdd(&acc[HC + c], q);
    }
}

// ---------------- bn2 apply (in place) + first conv3 transform ----------------
__global__ __launch_bounds__(256) void k_bnapply_mm(float* __restrict__ h, const float* __restrict__ acc,
                                                    const float* __restrict__ g, const float* __restrict__ b,
                                                    const float* __restrict__ W, float* __restrict__ out) {
    __shared__ float wl[HC * HC];
    __shared__ float il[8][HC];
    int t = threadIdx.x;
    for (int i = t; i < HC * HC; i += 256) wl[i] = W[i];
    int slot = t >> 5, c = t & 31;
    int n = blockIdx.x * 8 + slot;
    float mu = acc[c] * (1.f / NN);
    float var = acc[HC + c] * (1.f / NN) - mu * mu;
    float v = (h[n * HC + c] - mu) * rsqrtf(var + 1e-5f) * g[c] + b[c];
    h[n * HC + c] = v;
    il[slot][c] = v;
    __syncthreads();
    float s = 0.f;
#pragma unroll
    for (int k = 0; k < HC; k++) s += il[slot][k] * wl[k * HC + c];
    out[n * HC + c] = s;
}

// ---------------- conv4 initial: acc = h@W0, S = dinv*h ----------------
__global__ __launch_bounds__(256) void k_mm_tag(const float* __restrict__ in, const float* __restrict__ W,
                                                float* __restrict__ acc, float* __restrict__ S,
                                                const float* __restrict__ dinv) {
    __shared__ float wl[HC * HC];
    __shared__ float il[8][HC];
    int t = threadIdx.x;
    for (int i = t; i < HC * HC; i += 256) wl[i] = W[i];
    int slot = t >> 5, c = t & 31;
    int n = blockIdx.x * 8 + slot;
    float v = in[n * HC + c];
    il[slot][c] = v;
    S[n * HC + c] = dinv[n] * v;
    __syncthreads();
    float s = 0.f;
#pragma unroll
    for (int k = 0; k < HC; k++) s += il[slot][k] * wl[k * HC + c];
    acc[n * HC + c] = s;
}

// ---------------- TAG hop on pre-scaled S; LAST fuses b4 + softplus(lin4) ----------------
template <bool LAST>
__global__ __launch_bounds__(256) void k_tag(const float* __restrict__ S, float* __restrict__ Snew,
                                             float* __restrict__ acc, const float* __restrict__ Wk,
                                             const int* __restrict__ rowstart, const int* __restrict__ csr_src,
                                             const float* __restrict__ dinv,
                                             const float* __restrict__ b4, const float* __restrict__ l4w,
                                             const float* __restrict__ l4b, float* __restrict__ out) {
    __shared__ float wl[HC * HC];
    __shared__ float w2[LAST ? HC * HC : 1];
    __shared__ float cl[8][HC];
    int t = threadIdx.x;
    for (int i = t; i < HC * HC; i += 256) wl[i] = Wk[i];
    if (LAST) {
        for (int i = t; i < HC * HC; i += 256) w2[i] = l4w[i];
    }
    int slot = t >> 5, c = t & 31;
    int n = blockIdx.x * 8 + slot;
    int rs = rowstart[n], re = rowstart[n + 1];
    float s = 0.f;
    int e = rs;
    for (; e + 3 < re; e += 4) {
        int s0 = csr_src[e], s1 = csr_src[e + 1], s2 = csr_src[e + 2], s3 = csr_src[e + 3];
        s += S[s0 * HC + c] + S[s1 * HC + c] + S[s2 * HC + c] + S[s3 * HC + c];
    }
    for (; e < re; e++) s += S[csr_src[e] * HC + c];
    float di = dinv[n];
    float curnew = di * s;
    if (!LAST) Snew[n * HC + c] = di * curnew;
    cl[slot][c] = curnew;
    __syncthreads();
    float o = 0.f;
#pragma unroll
    for (int k = 0; k < HC; k++) o += cl[slot][k] * wl[k * HC + c];
    if (!LAST) {
        acc[n * HC + c] += o;
    } else {
        float tmp = acc[n * HC + c] + o + b4[c];
        __syncthreads();
        cl[slot][c] = tmp;
        __syncthreads();
        float o2 = l4b[c];
#pragma unroll
        for (int k = 0; k < HC; k++) o2 += cl[slot][k] * w2[k * HC + c];
        out[n * HC + c] = softplusf(o2);
    }
}

// ---------------- conv5: SAGE var-aggr + fused softplus(lin5) ----------------
__global__ __launch_bounds__(256) void k_sage(const float* __restrict__ h, float* __restrict__ out,
                                              const int* __restrict__ rowstart, const int* __restrict__ csr_src,
                                              const float* __restrict__ lw, const float* __restrict__ lb,
                                              const float* __restrict__ rw_, const float* __restrict__ l5w,
                                              const float* __restrict__ l5b) {
    __shared__ float wl[HC * HC], wr[HC * HC], w5[HC * HC];
    __shared__ float vl[8][HC], hl[8][HC];
    int t = threadIdx.x;
    for (int i = t; i < HC * HC; i += 256) {
        wl[i] = lw[i];
        wr[i] = rw_[i];
        w5[i] = l5w[i];
    }
    int slot = t >> 5, c = t & 31;
    int n = blockIdx.x * 8 + slot;
    int rs = rowstart[n], re = rowstart[n + 1];
    float s = 0.f, q = 0.f;
    int e = rs;
    for (; e + 3 < re; e += 4) {
        int s0 = csr_src[e], s1 = csr_src[e + 1], s2 = csr_src[e + 2], s3 = csr_src[e + 3];
        float v0 = h[s0 * HC + c], v1 = h[s1 * HC + c];
        float v2 = h[s2 * HC + c], v3 = h[s3 * HC + c];
        s += v0 + v1 + v2 + v3;
        q += v0 * v0 + v1 * v1 + v2 * v2 + v3 * v3;
    }
    for (; e < re; e++) {
        float v = h[csr_src[e] * HC + c];
        s += v;
        q += v * v;
    }
    float dc = fmaxf((float)(re - rs), 1.f);
    float mean = s / dc, mean2 = q / dc;
    float var = mean2 - mean * mean;
    float hv = h[n * HC + c];
    vl[slot][c] = var;
    hl[slot][c] = hv;
    __syncthreads();
    float o = lb[c];
#pragma unroll
    for (int k = 0; k < HC; k++) o += vl[slot][k] * wl[k * HC + c] + hl[slot][k] * wr[k * HC + c];
    __syncthreads();
    vl[slot][c] = o;
    __syncthreads();
    float o2 = l5b[c];
#pragma unroll
    for (int k = 0; k < HC; k++) o2 += vl[slot][k] * w5[k * HC + c];
    out[n * HC + c] = softplusf(o2);
}

// ---------------- per-graph InstanceNorm + global max pool + final linear ----------------
__global__ __launch_bounds__(256) void k_final(const float* __restrict__ h, const int* __restrict__ batch,
                                               const float* __restrict__ linw, const float* __restrict__ linb,
                                               float* __restrict__ out) {
    __shared__ float r1[8][HC];
    __shared__ float r2[8][HC];
    __shared__ float gmv[HC], grs[HC], pooled[HC];
    int g = blockIdx.x;
    int t = threadIdx.x, slot = t >> 5, c = t & 31;
    int lo = 0, hi = NN;
    while (lo < hi) {
        int mid = (lo + hi) >> 1;
        if (batch[mid] < g) lo = mid + 1;
        else hi = mid;
    }
    int start = lo;
    hi = NN;
    while (lo < hi) {
        int mid = (lo + hi) >> 1;
        if (batch[mid] <= g) lo = mid + 1;
        else hi = mid;
    }
    int end = lo;
    int cnt = end - start;
    float s = 0.f, q = 0.f;
    for (int n = start + slot; n < end; n += 8) {
        float v = h[n * HC + c];
        s += v;
        q += v * v;
    }
    r1[slot][c] = s;
    r2[slot][c] = q;
    __syncthreads();
    if (slot == 0) {
        for (int i = 1; i < 8; i++) {
            s += r1[i][c];
            q += r2[i][c];
        }
        float dc = (cnt > 0) ? (float)cnt : 1.f;
        float m = s / dc;
        float v = fmaxf(q / dc - m * m, 0.f);
        gmv[c] = m;
        grs[c] = rsqrtf(v + 1e-5f);
    }
    __syncthreads();
    float m_ = gmv[c], r_ = grs[c];
    float mx = -3.0e38f;
    for (int n = start + slot; n < end; n += 8) mx = fmaxf(mx, (h[n * HC + c] - m_) * r_);
    r1[slot][c] = mx;
    __syncthreads();
    if (slot == 0) {
        for (int i = 1; i < 8; i++) mx = fmaxf(mx, r1[i][c]);
        pooled[c] = (cnt > 0) ? mx : 0.f;
    }
    __syncthreads();
    if (t < 2) {
        float o = linb[t];
        for (int k = 0; k < HC; k++) o += pooled[k] * linw[k * 2 + t];
        out[g * 2 + t] = o;
    }
}

// ---------------- launch ----------------

extern "C" void kernel_launch(void* const* d_in, const int* in_sizes, int n_in,
                              void* d_out, int out_size, void* d_ws, size_t ws_size,
                              hipStream_t stream) {
    const int*   x      = (const int*)d_in[0];
    const int*   ei     = (const int*)d_in[1];
    const int*   batch  = (const int*)d_in[2];
    const float* emb    = (const float*)d_in[3];
    const float* w1     = (const float*)d_in[4];
    const float* g1wih  = (const float*)d_in[5];
    const float* g1whh  = (const float*)d_in[6];
    const float* g1bih  = (const float*)d_in[7];
    const float* g1bhh  = (const float*)d_in[8];
    const float* rel_w  = (const float*)d_in[9];
    const float* rel_b  = (const float*)d_in[10];
    const float* root_w = (const float*)d_in[11];
    const float* bn2g   = (const float*)d_in[12];
    const float* bn2b   = (const float*)d_in[13];
    const float* w3     = (const float*)d_in[14];
    const float* g3wih  = (const float*)d_in[15];
    const float* g3whh  = (const float*)d_in[16];
    const float* g3bih  = (const float*)d_in[17];
    const float* g3bhh  = (const float*)d_in[18];
    const float* lin3w  = (const float*)d_in[19];
    const float* lin3b  = (const float*)d_in[20];
    const float* w4     = (const float*)d_in[21];
    const float* b4     = (const float*)d_in[22];
    const float* lin4w  = (const float*)d_in[23];
    const float* lin4b  = (const float*)d_in[24];
    const float* sagelw = (const float*)d_in[25];
    const float* sagelb = (const float*)d_in[26];
    const float* sagerw = (const float*)d_in[27];
    const float* lin5w  = (const float*)d_in[28];
    const float* lin5b  = (const float*)d_in[29];
    const float* linw   = (const float*)d_in[30];
    const float* linb   = (const float*)d_in[31];

    const int* src = ei;
    const int* dst = ei + NE;

    char* ws = (char*)d_ws;
    size_t off = 0;
    int* deg = (int*)(ws + off); off += (size_t)NN * 4;
    int* cursor = (int*)(ws + off); off += (size_t)NN * 4;
    float* bnacc = (float*)(ws + off); off += 64 * 4;
    size_t zbytes = off;
    int* rowstart = (int*)(ws + off); off += (size_t)(NN + 1) * 4;
    float* dinv = (float*)(ws + off); off += (size_t)NN * 4;
    int* csr = (int*)(ws + off); off += (size_t)NE * 4;
    float* A = (float*)(ws + off); off += (size_t)NN * HC * 4;
    float* B = (float*)(ws + off); off += (size_t)NN * HC * 4;
    float* C = (float*)(ws + off); off += (size_t)NN * HC * 4;

    hipMemsetAsync(ws, 0, zbytes, stream);

    int ngE = (NE + 255) / 256;
    int ngN8 = NN / 8;       // 6250, exact
    int ngNC = NN * HC / 256;

    k_deg<<<ngE, 256, 0, stream>>>(dst, deg);
    k_scan<<<1, 1024, 0, stream>>>(deg, rowstart, dinv);
    k_csr<<<ngE, 256, 0, stream>>>(src, dst, rowstart, cursor, csr);
    k_atom<<<ngNC, 256, 0, stream>>>(x, emb, A);

    // conv1: GatedGraphConv(4, min); h = A; transformed feature ping-pongs B/C
    k_mm<<<ngN8, 256, 0, stream>>>(A, w1, B);
    k_agg_gru<0, false, 1><<<ngN8, 256, 0, stream>>>(B, A, rowstart, csr, g1wih, g1whh, g1bih, g1bhh,
                                                     w1 + 1 * HC * HC, nullptr, C);
    k_agg_gru<0, false, 1><<<ngN8, 256, 0, stream>>>(C, A, rowstart, csr, g1wih, g1whh, g1bih, g1bhh,
                                                     w1 + 2 * HC * HC, nullptr, B);
    k_agg_gru<0, false, 1><<<ngN8, 256, 0, stream>>>(B, A, rowstart, csr, g1wih, g1whh, g1bih, g1bhh,
                                                     w1 + 3 * HC * HC, nullptr, C);
    k_agg_gru<0, true, 0><<<ngN8, 256, 0, stream>>>(C, A, rowstart, csr, g1wih, g1whh, g1bih, g1bhh,
                                                    nullptr, nullptr, nullptr);

    // conv2 + elu -> B; bn2 stats; bn apply (in place) + A = Bn @ w3[0]
    k_conv2<<<ngN8, 256, 0, stream>>>(A, B, rowstart, csr, rel_w, rel_b, root_w);
    k_bnred<<<256, 256, 0, stream>>>(B, bnacc);
    k_bnapply_mm<<<ngN8, 256, 0, stream>>>(B, bnacc, bn2g, bn2b, w3, A);

    // conv3: GatedGraphConv(5, mul); h = B; last layer fuses relu(lin3) -> C
    k_agg_gru<1, false, 1><<<ngN8, 256, 0, stream>>>(A, B, rowstart, csr, g3wih, g3whh, g3bih, g3bhh,
                                                     w3 + 1 * HC * HC, nullptr, C);
    k_agg_gru<1, false, 1><<<ngN8, 256, 0, stream>>>(C, B, rowstart, csr, g3wih, g3whh, g3bih, g3bhh,
                                                     w3 + 2 * HC * HC, nullptr, A);
    k_agg_gru<1, false, 1><<<ngN8, 256, 0, stream>>>(A, B, rowstart, csr, g3wih, g3whh, g3bih, g3bhh,
                                                     w3 + 3 * HC * HC, nullptr, C);
    k_agg_gru<1, false, 1><<<ngN8, 256, 0, stream>>>(C, B, rowstart, csr, g3wih, g3whh, g3bih, g3bhh,
                                                     w3 + 4 * HC * HC, nullptr, A);
    k_agg_gru<1, false, 2><<<ngN8, 256, 0, stream>>>(A, B, rowstart, csr, g3wih, g3whh, g3bih, g3bhh,
                                                     lin3w, lin3b, C);

    // conv4: TAGConv K=7; h = C; acc = B; S ping-pongs A/C; out -> C
    k_mm_tag<<<ngN8, 256, 0, stream>>>(C, w4, B, A, dinv);
    {
        float* Scur = A;
        float* Snxt = C;
        for (int k = 1; k <= 6; k++) {
            k_tag<false><<<ngN8, 256, 0, stream>>>(Scur, Snxt, B, w4 + (size_t)k * HC * HC,
                                                   rowstart, csr, dinv, nullptr, nullptr, nullptr, nullptr);
            float* tmp = Scur; Scur = Snxt; Snxt = tmp;
        }
        // after 6 hops S is back in A
        k_tag<true><<<ngN8, 256, 0, stream>>>(Scur, nullptr, B, w4 + (size_t)7 * HC * HC,
                                              rowstart, csr, dinv, b4, lin4w, lin4b, C);
    }

    // conv5: SAGE var-aggr + softplus(lin5); h = C -> A
    k_sage<<<ngN8, 256, 0, stream>>>(C, A, rowstart, csr, sagelw, sagelb, sagerw, lin5w, lin5b);

    // bn5 (per-graph InstanceNorm) + max pool + final linear
    k_final<<<NG, 256, 0, stream>>>(A, batch, linw, linb, (float*)d_out);
}